// Round 4
// baseline (1283.172 us; speedup 1.0000x reference)
//
#include <hip/hip_runtime.h>
#include <hip/hip_cooperative_groups.h>

namespace cg = cooperative_groups;

// B=32, IN=16, C=8192, U=32, K=16, 3 routing iterations.
#define CC   8192
#define UU   32
#define BB   32
#define INU  16
#define UK   512
#define CPB  32      // channels per block
#define NBLK 256     // 1 block per CU, all co-resident (cooperative)
#define HALF 16      // x-staging half (channels)
#define XSTR 532     // x staging row stride in floats (532%32=20 -> 2-way max on writes)

template <int CTRL>
__device__ __forceinline__ float dpp_add(float x) {
  int p = __builtin_amdgcn_update_dpp(0, __float_as_int(x), CTRL, 0xF, 0xF, true);
  return x + __int_as_float(p);
}

// Sum over all 64 lanes (result in every lane). Rows of 16 via DPP (VALU pipe),
// then xor16/xor32 via shfl.
__device__ __forceinline__ float red64(float a) {
  a = dpp_add<0xB1>(a);    // quad_perm [1,0,3,2] : ^1
  a = dpp_add<0x4E>(a);    // quad_perm [2,3,0,1] : ^2
  a = dpp_add<0x141>(a);   // row_half_mirror     : ^7
  a = dpp_add<0x140>(a);   // row_mirror          : ^15
  a += __shfl_xor(a, 16);
  a += __shfl_xor(a, 32);
  return a;
}

// One kernel does all 3 routing iterations with grid-wide syncs.
// Lane map: k=l&15, bg=l>>4 (8 b's each); wave w owns u0=2w (|u|=2 per thread).
// b-logits for this block's 32 channels live in lanes 0..31 of b0/b1 (per wave).
// Pass p accumulates into S/Z slot p (pre-zeroed by one memset).
__global__ __launch_bounds__(1024, 4) void caps_all(
    const float* __restrict__ x, const float* __restrict__ W,
    float* __restrict__ Sg, float* __restrict__ Zg, float* __restrict__ out)
{
  __shared__ float xs[HALF * XSTR];   // 34048 B
  __shared__ float msq[BB * 16];      // 2 KB

  const int t  = threadIdx.x;
  const int l  = t & 63;
  const int k  = l & 15;
  const int bg = l >> 4;
  const int u0 = (t >> 6) * 2;
  const int c0 = blockIdx.x * CPB;

  float b0 = 0.f, b1 = 0.f;           // logits, lane cc holds channel c0+cc
  float v0[8], v1[8];                 // v[j][bb]; zero => pass0 gives uniform softmax exactly
#pragma unroll
  for (int bb = 0; bb < 8; ++bb) { v0[bb] = 0.f; v1[bb] = 0.f; }

  cg::grid_group grid = cg::this_grid();

#pragma unroll 1
  for (int pass = 0; pass < 3; ++pass) {
    float* S = Sg + pass * (BB * UK);
    float* Z = Zg + pass * UU;
    const int dir = pass & 1;         // serpentine: odd passes walk channels backward (L3 reuse)

    float Sl0[8], Sl1[8];
#pragma unroll
    for (int bb = 0; bb < 8; ++bb) { Sl0[bb] = 0.f; Sl1[bb] = 0.f; }
    float z0 = 0.f, z1 = 0.f;

#pragma unroll 1
    for (int hh = 0; hh < 2; ++hh) {
      const int h = dir ? (1 - hh) : hh;
      const int cbase = c0 + h * HALF;
      __syncthreads();
#pragma unroll
      for (int jj = 0; jj < 8; ++jj) {          // stage 16 channels of x
        int idx = jj * 1024 + t;
        int ccl = idx & 15, bi = idx >> 4;
        int b = bi >> 4, i = bi & 15;
        xs[ccl * XSTR + (b & 7) * 64 + (b >> 3) * 16 + i] = x[bi * CC + cbase + ccl];
      }
      __syncthreads();

#pragma unroll 1
      for (int ci = 0; ci < HALF; ++ci) {
        const int ccl = dir ? (HALF - 1 - ci) : ci;
        const int c   = cbase + ccl;
        const int cc  = h * HALF + ccl;          // 0..31 within block

        // W rows u0 and u0+1 at this k: 8 dwordx4
        const float4* wp = (const float4*)(W + ((size_t)c * UK + u0 * 16 + k) * INU);
        float4 wa0 = wp[0],  wa1 = wp[1],  wa2 = wp[2],  wa3 = wp[3];
        float4 wb0 = wp[64], wb1 = wp[65], wb2 = wp[66], wb3 = wp[67];

        float uh0[8], uh1[8];
        float ap0 = 0.f, ap1 = 0.f;
        const float* xr0 = xs + ccl * XSTR + bg * 16;
#pragma unroll
        for (int bb = 0; bb < 8; ++bb) {
          const float4* xr = (const float4*)(xr0 + bb * 64);
          float4 x0 = xr[0], x1 = xr[1], x2 = xr[2], x3 = xr[3];
          float h0, h1;
          h0 = wa0.x * x0.x;
          h0 = fmaf(wa0.y, x0.y, h0); h0 = fmaf(wa0.z, x0.z, h0); h0 = fmaf(wa0.w, x0.w, h0);
          h0 = fmaf(wa1.x, x1.x, h0); h0 = fmaf(wa1.y, x1.y, h0);
          h0 = fmaf(wa1.z, x1.z, h0); h0 = fmaf(wa1.w, x1.w, h0);
          h0 = fmaf(wa2.x, x2.x, h0); h0 = fmaf(wa2.y, x2.y, h0);
          h0 = fmaf(wa2.z, x2.z, h0); h0 = fmaf(wa2.w, x2.w, h0);
          h0 = fmaf(wa3.x, x3.x, h0); h0 = fmaf(wa3.y, x3.y, h0);
          h0 = fmaf(wa3.z, x3.z, h0); h0 = fmaf(wa3.w, x3.w, h0);
          h1 = wb0.x * x0.x;
          h1 = fmaf(wb0.y, x0.y, h1); h1 = fmaf(wb0.z, x0.z, h1); h1 = fmaf(wb0.w, x0.w, h1);
          h1 = fmaf(wb1.x, x1.x, h1); h1 = fmaf(wb1.y, x1.y, h1);
          h1 = fmaf(wb1.z, x1.z, h1); h1 = fmaf(wb1.w, x1.w, h1);
          h1 = fmaf(wb2.x, x2.x, h1); h1 = fmaf(wb2.y, x2.y, h1);
          h1 = fmaf(wb2.z, x2.z, h1); h1 = fmaf(wb2.w, x2.w, h1);
          h1 = fmaf(wb3.x, x3.x, h1); h1 = fmaf(wb3.y, x3.y, h1);
          h1 = fmaf(wb3.z, x3.z, h1); h1 = fmaf(wb3.w, x3.w, h1);
          uh0[bb] = h0; uh1[bb] = h1;
          ap0 = fmaf(h0, v0[bb], ap0);
          ap1 = fmaf(h1, v1[bb], ap1);
        }

        ap0 = red64(ap0);
        ap1 = red64(ap1);

        // Logit update: bn is identical in every lane (readlane broadcast +
        // lane-uniform ap), so lane cc just keeps its copy — no writelane needed.
        float bo0 = __int_as_float(__builtin_amdgcn_readlane(__float_as_int(b0), cc));
        float bo1 = __int_as_float(__builtin_amdgcn_readlane(__float_as_int(b1), cc));
        float bn0 = fmaf(ap0, 0.03125f, bo0);
        float bn1 = fmaf(ap1, 0.03125f, bo1);
        b0 = (l == cc) ? bn0 : b0;
        b1 = (l == cc) ? bn1 : b1;
        float e0 = __expf(bn0);
        float e1 = __expf(bn1);
        z0 += e0; z1 += e1;
#pragma unroll
        for (int bb = 0; bb < 8; ++bb) {
          Sl0[bb] = fmaf(e0, uh0[bb], Sl0[bb]);
          Sl1[bb] = fmaf(e1, uh1[bb], Sl1[bb]);
        }
      }
    }

    // Flush partials (coalesced lane-contiguous atomics)
#pragma unroll
    for (int bb = 0; bb < 8; ++bb) {
      atomicAdd(S + (bg * 8 + bb) * UK + u0 * 16 + k,       Sl0[bb]);
      atomicAdd(S + (bg * 8 + bb) * UK + (u0 + 1) * 16 + k, Sl1[bb]);
    }
    if (l == 0) { atomicAdd(Z + u0, z0); atomicAdd(Z + u0 + 1, z1); }

    __threadfence();
    grid.sync();

    if (pass < 2) {
      // In-block squash: mag_sq[b,k] = sum_u (S/Z)^2, then v regs for next pass.
      if (t < 512) msq[t] = 0.f;
      __syncthreads();
      {
        const int b = t >> 5, uu2 = t & 31;
        float rz = 1.0f / Z[uu2];
        const float4* sp = (const float4*)(S + t * 16);
        float4 s0 = sp[0], s1 = sp[1], s2 = sp[2], s3 = sp[3];
        float* mrow = msq + b * 16;
        float q;
        q = s0.x * rz; atomicAdd(mrow + 0,  q * q);
        q = s0.y * rz; atomicAdd(mrow + 1,  q * q);
        q = s0.z * rz; atomicAdd(mrow + 2,  q * q);
        q = s0.w * rz; atomicAdd(mrow + 3,  q * q);
        q = s1.x * rz; atomicAdd(mrow + 4,  q * q);
        q = s1.y * rz; atomicAdd(mrow + 5,  q * q);
        q = s1.z * rz; atomicAdd(mrow + 6,  q * q);
        q = s1.w * rz; atomicAdd(mrow + 7,  q * q);
        q = s2.x * rz; atomicAdd(mrow + 8,  q * q);
        q = s2.y * rz; atomicAdd(mrow + 9,  q * q);
        q = s2.z * rz; atomicAdd(mrow + 10, q * q);
        q = s2.w * rz; atomicAdd(mrow + 11, q * q);
        q = s3.x * rz; atomicAdd(mrow + 12, q * q);
        q = s3.y * rz; atomicAdd(mrow + 13, q * q);
        q = s3.z * rz; atomicAdd(mrow + 14, q * q);
        q = s3.w * rz; atomicAdd(mrow + 15, q * q);
      }
      __syncthreads();
      {
        float rz0 = 1.0f / Z[u0], rz1 = 1.0f / Z[u0 + 1];
#pragma unroll
        for (int bb = 0; bb < 8; ++bb) {
          int b = bg * 8 + bb;
          float m = msq[b * 16 + k];
          float g = sqrtf(m) / (1.0f + m);   // v = s*mag/(1+mag_sq)
          v0[bb] = S[b * UK + u0 * 16 + k] * rz0 * g;
          v1[bb] = S[b * UK + (u0 + 1) * 16 + k] * rz1 * g;
        }
      }
    } else if (blockIdx.x == 0) {
      // Final squash + output write by block 0 only.
      if (t < 512) msq[t] = 0.f;
      __syncthreads();
      const int b = t >> 5, uu2 = t & 31;
      float rz = 1.0f / Z[uu2];
      const float4* sp = (const float4*)(S + t * 16);
      float4 s0 = sp[0], s1 = sp[1], s2 = sp[2], s3 = sp[3];
      s0.x *= rz; s0.y *= rz; s0.z *= rz; s0.w *= rz;
      s1.x *= rz; s1.y *= rz; s1.z *= rz; s1.w *= rz;
      s2.x *= rz; s2.y *= rz; s2.z *= rz; s2.w *= rz;
      s3.x *= rz; s3.y *= rz; s3.z *= rz; s3.w *= rz;
      float* mrow = msq + b * 16;
      atomicAdd(mrow + 0,  s0.x * s0.x); atomicAdd(mrow + 1,  s0.y * s0.y);
      atomicAdd(mrow + 2,  s0.z * s0.z); atomicAdd(mrow + 3,  s0.w * s0.w);
      atomicAdd(mrow + 4,  s1.x * s1.x); atomicAdd(mrow + 5,  s1.y * s1.y);
      atomicAdd(mrow + 6,  s1.z * s1.z); atomicAdd(mrow + 7,  s1.w * s1.w);
      atomicAdd(mrow + 8,  s2.x * s2.x); atomicAdd(mrow + 9,  s2.y * s2.y);
      atomicAdd(mrow + 10, s2.z * s2.z); atomicAdd(mrow + 11, s2.w * s2.w);
      atomicAdd(mrow + 12, s3.x * s3.x); atomicAdd(mrow + 13, s3.y * s3.y);
      atomicAdd(mrow + 14, s3.z * s3.z); atomicAdd(mrow + 15, s3.w * s3.w);
      __syncthreads();
      float4 o0, o1, o2, o3;
      o0.x = s0.x * sqrtf(mrow[0])  / (1.0f + mrow[0]);
      o0.y = s0.y * sqrtf(mrow[1])  / (1.0f + mrow[1]);
      o0.z = s0.z * sqrtf(mrow[2])  / (1.0f + mrow[2]);
      o0.w = s0.w * sqrtf(mrow[3])  / (1.0f + mrow[3]);
      o1.x = s1.x * sqrtf(mrow[4])  / (1.0f + mrow[4]);
      o1.y = s1.y * sqrtf(mrow[5])  / (1.0f + mrow[5]);
      o1.z = s1.z * sqrtf(mrow[6])  / (1.0f + mrow[6]);
      o1.w = s1.w * sqrtf(mrow[7])  / (1.0f + mrow[7]);
      o2.x = s2.x * sqrtf(mrow[8])  / (1.0f + mrow[8]);
      o2.y = s2.y * sqrtf(mrow[9])  / (1.0f + mrow[9]);
      o2.z = s2.z * sqrtf(mrow[10]) / (1.0f + mrow[10]);
      o2.w = s2.w * sqrtf(mrow[11]) / (1.0f + mrow[11]);
      o3.x = s3.x * sqrtf(mrow[12]) / (1.0f + mrow[12]);
      o3.y = s3.y * sqrtf(mrow[13]) / (1.0f + mrow[13]);
      o3.z = s3.z * sqrtf(mrow[14]) / (1.0f + mrow[14]);
      o3.w = s3.w * sqrtf(mrow[15]) / (1.0f + mrow[15]);
      float4* op = (float4*)(out + t * 16);
      op[0] = o0; op[1] = o1; op[2] = o2; op[3] = o3;
    }
  }
}

extern "C" void kernel_launch(void* const* d_in, const int* in_sizes, int n_in,
                              void* d_out, int out_size, void* d_ws, size_t ws_size,
                              hipStream_t stream)
{
  const float* x = (const float*)d_in[0];   // (B, IN, C)
  const float* W = (const float*)d_in[1];   // (C, U, K, IN)
  float* out = (float*)d_out;               // (B, U, K, 1)

  float* Sg = (float*)d_ws;                               // 3 slots of 16384 floats
  float* Zg = (float*)((char*)d_ws + 3 * BB * UK * 4);    // 3 slots of 32 floats

  (void)hipMemsetAsync(d_ws, 0, 3 * BB * UK * 4 + 3 * UU * 4, stream);

  void* args[] = { (void*)&x, (void*)&W, (void*)&Sg, (void*)&Zg, (void*)&out };
  (void)hipLaunchCooperativeKernel(reinterpret_cast<void*>(caps_all),
                                   dim3(NBLK), dim3(1024), args, 0, stream);
}